// Round 4
// baseline (298.340 us; speedup 1.0000x reference)
//
#include <hip/hip_runtime.h>
#include <hip/hip_fp16.h>

typedef _Float16 half8 __attribute__((ext_vector_type(8)));
typedef float f32x4 __attribute__((ext_vector_type(4)));

constexpr int M = 2048;    // B*S
constexpr int N = 10240;   // DOUT
constexpr int K = 4096;    // DIN

// ---------------------------------------------------------------------------
// Pre-pass 1: W fp32 -> fp16 * fp16(scale). Bit-identical to reference.
__global__ __launch_bounds__(256)
void dequant_w_kernel(const float* __restrict__ W, const float* __restrict__ Wsc,
                      _Float16* __restrict__ Wh) {
    const long total = (long)N * K / 8;
    for (long i = (long)blockIdx.x * blockDim.x + threadIdx.x; i < total;
         i += (long)gridDim.x * blockDim.x) {
        const long base = i * 8;
        const int row = (int)(base >> 12);           // / K
        const _Float16 s = (_Float16)Wsc[row];
        const float4 w0 = ((const float4*)(W + base))[0];
        const float4 w1 = ((const float4*)(W + base))[1];
        half8 h;
        h[0] = (_Float16)w0.x * s; h[1] = (_Float16)w0.y * s;
        h[2] = (_Float16)w0.z * s; h[3] = (_Float16)w0.w * s;
        h[4] = (_Float16)w1.x * s; h[5] = (_Float16)w1.y * s;
        h[6] = (_Float16)w1.z * s; h[7] = (_Float16)w1.w * s;
        *(half8*)(Wh + base) = h;
    }
}

// Pre-pass 2: A fp32 (fp16-valued) -> fp16 (exact).
__global__ __launch_bounds__(256)
void convert_a_kernel(const float* __restrict__ A, _Float16* __restrict__ Ah) {
    const long total = (long)M * K / 8;
    for (long i = (long)blockIdx.x * blockDim.x + threadIdx.x; i < total;
         i += (long)gridDim.x * blockDim.x) {
        const long base = i * 8;
        const float4 a0 = ((const float4*)(A + base))[0];
        const float4 a1 = ((const float4*)(A + base))[1];
        half8 h;
        h[0] = (_Float16)a0.x; h[1] = (_Float16)a0.y;
        h[2] = (_Float16)a0.z; h[3] = (_Float16)a0.w;
        h[4] = (_Float16)a1.x; h[5] = (_Float16)a1.y;
        h[6] = (_Float16)a1.z; h[7] = (_Float16)a1.w;
        *(half8*)(Ah + base) = h;
    }
}

// ---------------------------------------------------------------------------
// 8-phase-style GEMM: BM=128, BN=256, BK=64, 8 waves (2M x 4N), dbuf LDS.
// T2 swizzle: global_load_lds writes LINEARLY; source column pre-swizzled
// (slot ^= row&7); ds_read applies the same XOR. T5 setprio around MFMA.
constexpr int BM = 128, BN = 256, BK = 64;
constexpr int AELE = BM * BK;   // 8192 fp16 = 16 KB
constexpr int BELE = BN * BK;   // 16384 fp16 = 32 KB
constexpr int NT = K / BK;      // 64 K-tiles

#define PHASE_BARRIER() asm volatile("s_barrier" ::: "memory")

__device__ __forceinline__ half8 lds_rd(const _Float16* base, int row, int eo) {
    // eo = element offset in row (multiple of 8); physical slot = slot ^ (row&7)
    const int ps = (eo >> 3) ^ (row & 7);
    return *(const half8*)(base + row * BK + ps * 8);
}

__global__ __launch_bounds__(512, 2)
void qgemm8p_kernel(const _Float16* __restrict__ Ag,  // [M,K] fp16 (ws)
                    const _Float16* __restrict__ Wg,  // [N,K] fp16 dequant (ws)
                    const float*    __restrict__ bias,
                    float*          __restrict__ C)
{
    __shared__ _Float16 AsF[2 * AELE];   // 32 KB
    __shared__ _Float16 BsF[2 * BELE];   // 64 KB

    // XCD-bijective swizzle: nwg=640, 640%8==0, chunks of 80; brow-fast order
    // so 16 consecutive blocks in a chunk share one 2MB B panel (fits L2).
    const int orig = blockIdx.x;
    const int wgid = (orig & 7) * 80 + (orig >> 3);
    const int m0 = (wgid & 15) * BM;
    const int n0 = (wgid >> 4) * BN;

    const int tid  = threadIdx.x;
    const int lane = tid & 63;
    const int w    = tid >> 6;
    const int wm   = w >> 2;            // 0..1 -> rows wm*64
    const int wn   = w & 3;             // 0..3 -> cols wn*64
    const int fr   = lane & 15;
    const int fkE  = (lane >> 4) * 8;   // element offset of k-fragment

    const int trow  = tid >> 3;                              // staging row 0..63
    const int swcol = (((tid & 7) ^ (trow & 7))) * 8;        // pre-swizzled col

    // staging helpers (linear LDS dest, swizzled global source)
    auto stage_a = [&](int b, int h, int kcol) {
        const _Float16* src = Ag + (size_t)(m0 + h * 64 + trow) * K + (kcol + swcol);
        __builtin_amdgcn_global_load_lds(
            (const __attribute__((address_space(1))) void*)src,
            (__attribute__((address_space(3))) void*)(AsF + b * AELE + h * 4096 + tid * 8),
            16, 0, 0);
    };
    auto stage_b = [&](int b, int h, int c, int kcol) {
        const int rbase = h * 128 + c * 64;
        const _Float16* src = Wg + (size_t)(n0 + rbase + trow) * K + (kcol + swcol);
        __builtin_amdgcn_global_load_lds(
            (const __attribute__((address_space(1))) void*)src,
            (__attribute__((address_space(3))) void*)(BsF + b * BELE + rbase * BK + tid * 8),
            16, 0, 0);
    };

    f32x4 acc[4][4];
#pragma unroll
    for (int i = 0; i < 4; ++i)
#pragma unroll
        for (int j = 0; j < 4; ++j)
            acc[i][j] = (f32x4){0.f, 0.f, 0.f, 0.f};

    // prologue: stage tile 0 into buf 0, full drain once
    stage_a(0, 0, 0); stage_a(0, 1, 0);
    stage_b(0, 0, 0, 0); stage_b(0, 0, 1, 0);
    stage_b(0, 1, 0, 0); stage_b(0, 1, 1, 0);
    __syncthreads();

    for (int t = 0; t < NT; ++t) {
        const int cur = t & 1, nxt = cur ^ 1;
        const _Float16* Ab = AsF + cur * AELE;
        const _Float16* Bb = BsF + cur * BELE;
        const bool pf = (t + 1 < NT);
        const int k1 = (t + 1) * BK;

        half8 a0[2][2], a1[2][2], b0[2][2], b1[2][2];

        // ---- phase 0: quadrant (0,0); prefetch A halves + B0c0
#pragma unroll
        for (int i2 = 0; i2 < 2; ++i2)
#pragma unroll
            for (int kh = 0; kh < 2; ++kh)
                a0[i2][kh] = lds_rd(Ab, wm * 64 + i2 * 16 + fr, kh * 32 + fkE);
#pragma unroll
        for (int j2 = 0; j2 < 2; ++j2)
#pragma unroll
            for (int kh = 0; kh < 2; ++kh)
                b0[j2][kh] = lds_rd(Bb, wn * 64 + j2 * 16 + fr, kh * 32 + fkE);
        if (pf) { stage_a(nxt, 0, k1); stage_a(nxt, 1, k1); stage_b(nxt, 0, 0, k1); }
        PHASE_BARRIER();
        __builtin_amdgcn_s_setprio(1);
#pragma unroll
        for (int i2 = 0; i2 < 2; ++i2)
#pragma unroll
            for (int j2 = 0; j2 < 2; ++j2)
#pragma unroll
                for (int kh = 0; kh < 2; ++kh)
                    acc[i2][j2] = __builtin_amdgcn_mfma_f32_16x16x32_f16(
                        a0[i2][kh], b0[j2][kh], acc[i2][j2], 0, 0, 0);
        __builtin_amdgcn_s_setprio(0);
        PHASE_BARRIER();

        // ---- phase 1: quadrant (0,1); prefetch B0c1 + B1c0
#pragma unroll
        for (int j2 = 0; j2 < 2; ++j2)
#pragma unroll
            for (int kh = 0; kh < 2; ++kh)
                b1[j2][kh] = lds_rd(Bb, wn * 64 + 32 + j2 * 16 + fr, kh * 32 + fkE);
        if (pf) { stage_b(nxt, 0, 1, k1); stage_b(nxt, 1, 0, k1); }
        PHASE_BARRIER();
        __builtin_amdgcn_s_setprio(1);
#pragma unroll
        for (int i2 = 0; i2 < 2; ++i2)
#pragma unroll
            for (int j2 = 0; j2 < 2; ++j2)
#pragma unroll
                for (int kh = 0; kh < 2; ++kh)
                    acc[i2][2 + j2] = __builtin_amdgcn_mfma_f32_16x16x32_f16(
                        a0[i2][kh], b1[j2][kh], acc[i2][2 + j2], 0, 0, 0);
        __builtin_amdgcn_s_setprio(0);
        PHASE_BARRIER();

        // ---- phase 2: quadrant (1,0); prefetch B1c1
#pragma unroll
        for (int i2 = 0; i2 < 2; ++i2)
#pragma unroll
            for (int kh = 0; kh < 2; ++kh)
                a1[i2][kh] = lds_rd(Ab, wm * 64 + 32 + i2 * 16 + fr, kh * 32 + fkE);
        if (pf) { stage_b(nxt, 1, 1, k1); }
        PHASE_BARRIER();
        __builtin_amdgcn_s_setprio(1);
#pragma unroll
        for (int i2 = 0; i2 < 2; ++i2)
#pragma unroll
            for (int j2 = 0; j2 < 2; ++j2)
#pragma unroll
                for (int kh = 0; kh < 2; ++kh)
                    acc[2 + i2][j2] = __builtin_amdgcn_mfma_f32_16x16x32_f16(
                        a1[i2][kh], b0[j2][kh], acc[2 + i2][j2], 0, 0, 0);
        __builtin_amdgcn_s_setprio(0);
        PHASE_BARRIER();

        // ---- phase 3: quadrant (1,1); all operands in registers
        __builtin_amdgcn_s_setprio(1);
#pragma unroll
        for (int i2 = 0; i2 < 2; ++i2)
#pragma unroll
            for (int j2 = 0; j2 < 2; ++j2)
#pragma unroll
                for (int kh = 0; kh < 2; ++kh)
                    acc[2 + i2][2 + j2] = __builtin_amdgcn_mfma_f32_16x16x32_f16(
                        a1[i2][kh], b1[j2][kh], acc[2 + i2][2 + j2], 0, 0, 0);
        __builtin_amdgcn_s_setprio(0);

        // tile boundary: drains vmcnt (prefetch loads are >=1.3 phases old)
        __syncthreads();
    }

    // epilogue: C/D layout col = lane&15, row = (lane>>4)*4 + reg
#pragma unroll
    for (int i = 0; i < 4; ++i) {
        const int row = m0 + wm * 64 + i * 16 + (lane >> 4) * 4;
#pragma unroll
        for (int j = 0; j < 4; ++j) {
            const int col = n0 + wn * 64 + j * 16 + fr;
            const float bb = bias[col];
#pragma unroll
            for (int r = 0; r < 4; ++r)
                C[(size_t)(row + r) * N + col] =
                    (float)(_Float16)(acc[i][j][r] + bb);
        }
    }
}

// ---------------------------------------------------------------------------
// Fallback (round-2 fused kernel, passing @434us) if ws too small.
__global__ __launch_bounds__(256, 2)
void qlinear_fused_kernel(const float* __restrict__ A, const float* __restrict__ W,
                          const float* __restrict__ Wsc, const float* __restrict__ bias,
                          float* __restrict__ C)
{
    __shared__ _Float16 As[128][64];
    __shared__ _Float16 Bs[128][64];

    const int nwg  = (M / 128) * (N / 128);
    const int orig = blockIdx.x;
    const int wgid = (orig & 7) * (nwg >> 3) + (orig >> 3);
    const int brow = wgid & (M / 128 - 1);
    const int bcol = wgid / (M / 128);
    const int m0 = brow * 128;
    const int n0 = bcol * 128;

    const int t    = threadIdx.x;
    const int lane = t & 63;
    const int wave = t >> 6;
    const int wr = (wave >> 1) * 64;
    const int wc = (wave & 1) * 64;
    const int fr = lane & 15;
    const int fk = (lane >> 4) * 8;
    const int srow = t >> 3;
    const int scol = (t & 7) * 8;

    _Float16 hs[4];
#pragma unroll
    for (int p = 0; p < 4; ++p)
        hs[p] = (_Float16)Wsc[n0 + srow + p * 32];

    f32x4 acc[4][4];
#pragma unroll
    for (int i = 0; i < 4; ++i)
#pragma unroll
        for (int j = 0; j < 4; ++j)
            acc[i][j] = (f32x4){0.f, 0.f, 0.f, 0.f};

    for (int k0 = 0; k0 < K; k0 += 64) {
        __syncthreads();
#pragma unroll
        for (int c = 0; c < 4; ++c) {
            const int rl = c * 32 + srow;
            const float* asrc = A + (size_t)(m0 + rl) * K + (k0 + scol);
            const float4 a0 = ((const float4*)asrc)[0];
            const float4 a1 = ((const float4*)asrc)[1];
            half8 av;
            av[0] = (_Float16)a0.x; av[1] = (_Float16)a0.y;
            av[2] = (_Float16)a0.z; av[3] = (_Float16)a0.w;
            av[4] = (_Float16)a1.x; av[5] = (_Float16)a1.y;
            av[6] = (_Float16)a1.z; av[7] = (_Float16)a1.w;
            *(half8*)&As[rl][scol] = av;
        }
#pragma unroll
        for (int p = 0; p < 4; ++p) {
            const int nl = srow + p * 32;
            const float* wsrc = W + (size_t)(n0 + nl) * K + (k0 + scol);
            const float4 w0 = ((const float4*)wsrc)[0];
            const float4 w1 = ((const float4*)wsrc)[1];
            half8 hv;
            hv[0] = (_Float16)w0.x * hs[p]; hv[1] = (_Float16)w0.y * hs[p];
            hv[2] = (_Float16)w0.z * hs[p]; hv[3] = (_Float16)w0.w * hs[p];
            hv[4] = (_Float16)w1.x * hs[p]; hv[5] = (_Float16)w1.y * hs[p];
            hv[6] = (_Float16)w1.z * hs[p]; hv[7] = (_Float16)w1.w * hs[p];
            *(half8*)&Bs[nl][scol] = hv;
        }
        __syncthreads();
#pragma unroll
        for (int kk = 0; kk < 64; kk += 32) {
            half8 av[4], bv[4];
#pragma unroll
            for (int i = 0; i < 4; ++i)
                av[i] = *(const half8*)&As[wr + i * 16 + fr][kk + fk];
#pragma unroll
            for (int j = 0; j < 4; ++j)
                bv[j] = *(const half8*)&Bs[wc + j * 16 + fr][kk + fk];
#pragma unroll
            for (int i = 0; i < 4; ++i)
#pragma unroll
                for (int j = 0; j < 4; ++j)
                    acc[i][j] = __builtin_amdgcn_mfma_f32_16x16x32_f16(
                        av[i], bv[j], acc[i][j], 0, 0, 0);
        }
    }
#pragma unroll
    for (int i = 0; i < 4; ++i) {
        const int row = m0 + wr + i * 16 + (lane >> 4) * 4;
#pragma unroll
        for (int j = 0; j < 4; ++j) {
            const int col = n0 + wc + j * 16 + fr;
            const float bb = bias[col];
#pragma unroll
            for (int r = 0; r < 4; ++r)
                C[(size_t)(row + r) * N + col] =
                    (float)(_Float16)(acc[i][j][r] + bb);
        }
    }
}

extern "C" void kernel_launch(void* const* d_in, const int* in_sizes, int n_in,
                              void* d_out, int out_size, void* d_ws, size_t ws_size,
                              hipStream_t stream) {
    const float* A    = (const float*)d_in[0];
    const float* W    = (const float*)d_in[1];
    const float* Wsc  = (const float*)d_in[2];
    const float* bias = (const float*)d_in[3];
    float* C = (float*)d_out;

    const size_t a_bytes = (size_t)M * K * sizeof(_Float16);   // 16.78 MB
    const size_t w_bytes = (size_t)N * K * sizeof(_Float16);   // 83.89 MB

    if (ws_size >= a_bytes + w_bytes) {
        _Float16* Ah = (_Float16*)d_ws;
        _Float16* Wh = (_Float16*)((char*)d_ws + a_bytes);
        convert_a_kernel<<<dim3(1024), dim3(256), 0, stream>>>(A, Ah);
        dequant_w_kernel<<<dim3(2048), dim3(256), 0, stream>>>(W, Wsc, Wh);
        const int nwg = (M / BM) * (N / BN);  // 640
        qgemm8p_kernel<<<dim3(nwg), dim3(512), 0, stream>>>(Ah, Wh, bias, C);
    } else {
        const int nwg = (M / 128) * (N / 128);
        qlinear_fused_kernel<<<dim3(nwg), dim3(256), 0, stream>>>(A, W, Wsc, bias, C);
    }
}

// Round 5
// 281.779 us; speedup vs baseline: 1.0588x; 1.0588x over previous
//
#include <hip/hip_runtime.h>
#include <hip/hip_fp16.h>

typedef _Float16 half8 __attribute__((ext_vector_type(8)));
typedef float f32x4 __attribute__((ext_vector_type(4)));

constexpr int M = 2048;    // B*S
constexpr int N = 10240;   // DOUT
constexpr int K = 4096;    // DIN

// ---------------------------------------------------------------------------
// Pre-pass 1: W fp32 -> fp16 * fp16(scale). Bit-identical to reference.
__global__ __launch_bounds__(256)
void dequant_w_kernel(const float* __restrict__ W, const float* __restrict__ Wsc,
                      _Float16* __restrict__ Wh) {
    const long total = (long)N * K / 8;
    for (long i = (long)blockIdx.x * blockDim.x + threadIdx.x; i < total;
         i += (long)gridDim.x * blockDim.x) {
        const long base = i * 8;
        const int row = (int)(base >> 12);           // / K
        const _Float16 s = (_Float16)Wsc[row];
        const float4 w0 = ((const float4*)(W + base))[0];
        const float4 w1 = ((const float4*)(W + base))[1];
        half8 h;
        h[0] = (_Float16)w0.x * s; h[1] = (_Float16)w0.y * s;
        h[2] = (_Float16)w0.z * s; h[3] = (_Float16)w0.w * s;
        h[4] = (_Float16)w1.x * s; h[5] = (_Float16)w1.y * s;
        h[6] = (_Float16)w1.z * s; h[7] = (_Float16)w1.w * s;
        *(half8*)(Wh + base) = h;
    }
}

// Pre-pass 2: A fp32 (fp16-valued) -> fp16 (exact).
__global__ __launch_bounds__(256)
void convert_a_kernel(const float* __restrict__ A, _Float16* __restrict__ Ah) {
    const long total = (long)M * K / 8;
    for (long i = (long)blockIdx.x * blockDim.x + threadIdx.x; i < total;
         i += (long)gridDim.x * blockDim.x) {
        const long base = i * 8;
        const float4 a0 = ((const float4*)(A + base))[0];
        const float4 a1 = ((const float4*)(A + base))[1];
        half8 h;
        h[0] = (_Float16)a0.x; h[1] = (_Float16)a0.y;
        h[2] = (_Float16)a0.z; h[3] = (_Float16)a0.w;
        h[4] = (_Float16)a1.x; h[5] = (_Float16)a1.y;
        h[6] = (_Float16)a1.z; h[7] = (_Float16)a1.w;
        *(half8*)(Ah + base) = h;
    }
}

// ---------------------------------------------------------------------------
// Phase GEMM with counted vmcnt (T3+T4), T2 LDS swizzle, T5 setprio.
// BM=128, BN=256, BK=64, 8 waves (2M x 4N), double-buffered LDS (96 KB).
//
// Buffer lifetime ledger (correctness proof for distance-2 prefetch):
//   reads: a0,b0 @P0; b1 @P1; a1 @P2. Each wave's ds_reads complete before
//   its MFMA (data dep), which precedes its phase-end barrier. Hence:
//     - after P1-end barrier: ALL waves done reading B of buf cur
//     - after P2-end barrier: ALL waves done reading A of buf cur
//   stage B(t+2)->buf cur at P2 (after P1-end bar), stage A(t+2) at P3
//   (after P2-end bar). vmcnt(6) at P3 = wait for t+1's 6 loads while
//   t+2's 6 stay in flight; barrier publishes. Never drain to 0 mid-loop.
constexpr int BM = 128, BN = 256, BK = 64;
constexpr int AELE = BM * BK;   // 8192 fp16 = 16 KB
constexpr int BELE = BN * BK;   // 16384 fp16 = 32 KB
constexpr int NT = K / BK;      // 64 K-tiles

#define BAR()   asm volatile("s_barrier" ::: "memory")
#define LGKM0() asm volatile("s_waitcnt lgkmcnt(0)" ::: "memory")

__device__ __forceinline__ half8 lds_rd(const _Float16* base, int row, int eo) {
    // T2: physical 16B slot = slot ^ (row&7)
    const int ps = (eo >> 3) ^ (row & 7);
    return *(const half8*)(base + row * BK + ps * 8);
}

__global__ __launch_bounds__(512, 1)
void qgemm8p_kernel(const _Float16* __restrict__ Ag,  // [M,K] fp16 (ws)
                    const _Float16* __restrict__ Wg,  // [N,K] fp16 dequant (ws)
                    const float*    __restrict__ bias,
                    float*          __restrict__ C)
{
    __shared__ _Float16 AsF[2 * AELE];   // 32 KB
    __shared__ _Float16 BsF[2 * BELE];   // 64 KB

    // XCD-bijective swizzle: nwg=640, chunks of 80, brow-fast (16 consecutive
    // blocks share one 2MB B panel -> L2-resident per XCD).
    const int orig = blockIdx.x;
    const int wgid = (orig & 7) * 80 + (orig >> 3);
    const int m0 = (wgid & 15) * BM;
    const int n0 = (wgid >> 4) * BN;

    const int tid  = threadIdx.x;
    const int lane = tid & 63;
    const int w    = tid >> 6;
    const int wm   = w >> 2;            // 0..1
    const int wn   = w & 3;             // 0..3
    const int fr   = lane & 15;
    const int fkE  = (lane >> 4) * 8;

    const int trow  = tid >> 3;                        // staging row 0..63
    const int swcol = (((tid & 7) ^ (trow & 7))) * 8;  // pre-swizzled src col

    // stage unit = 64 contiguous rows (512 thr x 16B, linear LDS dest)
    auto stage_a = [&](int b, int h, int kcol) {
        const _Float16* src = Ag + (size_t)(m0 + h * 64 + trow) * K + (kcol + swcol);
        __builtin_amdgcn_global_load_lds(
            (const __attribute__((address_space(1))) void*)src,
            (__attribute__((address_space(3))) void*)(AsF + b * AELE + h * 4096 + tid * 8),
            16, 0, 0);
    };
    auto stage_b = [&](int b, int r4, int kcol) {
        const _Float16* src = Wg + (size_t)(n0 + r4 * 64 + trow) * K + (kcol + swcol);
        __builtin_amdgcn_global_load_lds(
            (const __attribute__((address_space(1))) void*)src,
            (__attribute__((address_space(3))) void*)(BsF + b * BELE + r4 * 4096 + tid * 8),
            16, 0, 0);
    };

    f32x4 acc[4][4];
#pragma unroll
    for (int i = 0; i < 4; ++i)
#pragma unroll
        for (int j = 0; j < 4; ++j)
            acc[i][j] = (f32x4){0.f, 0.f, 0.f, 0.f};

    // prologue: stage tile0 -> buf0 (6 loads), tile1 -> buf1 (6 loads)
    stage_a(0, 0, 0); stage_a(0, 1, 0);
    stage_b(0, 0, 0); stage_b(0, 1, 0); stage_b(0, 2, 0); stage_b(0, 3, 0);
    if (NT > 1) {
        stage_a(1, 0, BK); stage_a(1, 1, BK);
        stage_b(1, 0, BK); stage_b(1, 1, BK); stage_b(1, 2, BK); stage_b(1, 3, BK);
        asm volatile("s_waitcnt vmcnt(6)" ::: "memory");   // tile0 landed
    } else {
        asm volatile("s_waitcnt vmcnt(0)" ::: "memory");
    }
    BAR();

#pragma unroll 1
    for (int t = 0; t < NT; ++t) {
        const int cur = t & 1;
        const _Float16* Ab = AsF + cur * AELE;
        const _Float16* Bb = BsF + cur * BELE;
        const bool pf2 = (t + 2 < NT);
        const int k2 = (t + 2) * BK;

        half8 a0[2][2], a1[2][2], b0[2][2], b1[2][2];

        // ---- P0: read a0 + b0; MFMA quadrant (0,0)
#pragma unroll
        for (int i2 = 0; i2 < 2; ++i2)
#pragma unroll
            for (int kh = 0; kh < 2; ++kh)
                a0[i2][kh] = lds_rd(Ab, wm * 64 + i2 * 16 + fr, kh * 32 + fkE);
#pragma unroll
        for (int j2 = 0; j2 < 2; ++j2)
#pragma unroll
            for (int kh = 0; kh < 2; ++kh)
                b0[j2][kh] = lds_rd(Bb, wn * 64 + j2 * 16 + fr, kh * 32 + fkE);
        BAR(); LGKM0();
        __builtin_amdgcn_s_setprio(1);
#pragma unroll
        for (int i2 = 0; i2 < 2; ++i2)
#pragma unroll
            for (int j2 = 0; j2 < 2; ++j2)
#pragma unroll
                for (int kh = 0; kh < 2; ++kh)
                    acc[i2][j2] = __builtin_amdgcn_mfma_f32_16x16x32_f16(
                        a0[i2][kh], b0[j2][kh], acc[i2][j2], 0, 0, 0);
        __builtin_amdgcn_s_setprio(0);
        BAR();

        // ---- P1: read b1; MFMA quadrant (0,1)
#pragma unroll
        for (int j2 = 0; j2 < 2; ++j2)
#pragma unroll
            for (int kh = 0; kh < 2; ++kh)
                b1[j2][kh] = lds_rd(Bb, wn * 64 + 32 + j2 * 16 + fr, kh * 32 + fkE);
        BAR(); LGKM0();
        __builtin_amdgcn_s_setprio(1);
#pragma unroll
        for (int i2 = 0; i2 < 2; ++i2)
#pragma unroll
            for (int j2 = 0; j2 < 2; ++j2)
#pragma unroll
                for (int kh = 0; kh < 2; ++kh)
                    acc[i2][2 + j2] = __builtin_amdgcn_mfma_f32_16x16x32_f16(
                        a0[i2][kh], b1[j2][kh], acc[i2][2 + j2], 0, 0, 0);
        __builtin_amdgcn_s_setprio(0);
        BAR();   // <- after this, B of buf cur fully consumed

        // ---- P2: read a1; stage B(t+2) into buf cur; MFMA quadrant (1,0)
#pragma unroll
        for (int i2 = 0; i2 < 2; ++i2)
#pragma unroll
            for (int kh = 0; kh < 2; ++kh)
                a1[i2][kh] = lds_rd(Ab, wm * 64 + 32 + i2 * 16 + fr, kh * 32 + fkE);
        if (pf2) {
            stage_b(cur, 0, k2); stage_b(cur, 1, k2);
            stage_b(cur, 2, k2); stage_b(cur, 3, k2);
        }
        BAR(); LGKM0();
        __builtin_amdgcn_s_setprio(1);
#pragma unroll
        for (int i2 = 0; i2 < 2; ++i2)
#pragma unroll
            for (int j2 = 0; j2 < 2; ++j2)
#pragma unroll
                for (int kh = 0; kh < 2; ++kh)
                    acc[2 + i2][j2] = __builtin_amdgcn_mfma_f32_16x16x32_f16(
                        a1[i2][kh], b0[j2][kh], acc[2 + i2][j2], 0, 0, 0);
        __builtin_amdgcn_s_setprio(0);
        BAR();   // <- after this, A of buf cur fully consumed

        // ---- P3: stage A(t+2); MFMA quadrant (1,1); counted vmcnt; publish
        if (pf2) { stage_a(cur, 0, k2); stage_a(cur, 1, k2); }
        __builtin_amdgcn_s_setprio(1);
#pragma unroll
        for (int i2 = 0; i2 < 2; ++i2)
#pragma unroll
            for (int j2 = 0; j2 < 2; ++j2)
#pragma unroll
                for (int kh = 0; kh < 2; ++kh)
                    acc[2 + i2][2 + j2] = __builtin_amdgcn_mfma_f32_16x16x32_f16(
                        a1[i2][kh], b1[j2][kh], acc[2 + i2][2 + j2], 0, 0, 0);
        __builtin_amdgcn_s_setprio(0);
        if (pf2) asm volatile("s_waitcnt vmcnt(6)" ::: "memory");  // t+1 landed
        else     asm volatile("s_waitcnt vmcnt(0)" ::: "memory");  // tail drain
        BAR();
    }

    // epilogue: C/D layout col = lane&15, row = (lane>>4)*4 + reg
#pragma unroll
    for (int i = 0; i < 4; ++i) {
        const int row = m0 + wm * 64 + i * 16 + (lane >> 4) * 4;
#pragma unroll
        for (int j = 0; j < 4; ++j) {
            const int col = n0 + wn * 64 + j * 16 + fr;
            const float bb = bias[col];
#pragma unroll
            for (int r = 0; r < 4; ++r)
                C[(size_t)(row + r) * N + col] =
                    (float)(_Float16)(acc[i][j][r] + bb);
        }
    }
}

// ---------------------------------------------------------------------------
// Fallback (round-2 fused kernel, passing @434us) if ws too small.
__global__ __launch_bounds__(256, 2)
void qlinear_fused_kernel(const float* __restrict__ A, const float* __restrict__ W,
                          const float* __restrict__ Wsc, const float* __restrict__ bias,
                          float* __restrict__ C)
{
    __shared__ _Float16 As[128][64];
    __shared__ _Float16 Bs[128][64];

    const int nwg  = (M / 128) * (N / 128);
    const int orig = blockIdx.x;
    const int wgid = (orig & 7) * (nwg >> 3) + (orig >> 3);
    const int brow = wgid & (M / 128 - 1);
    const int bcol = wgid / (M / 128);
    const int m0 = brow * 128;
    const int n0 = bcol * 128;

    const int t    = threadIdx.x;
    const int lane = t & 63;
    const int wave = t >> 6;
    const int wr = (wave >> 1) * 64;
    const int wc = (wave & 1) * 64;
    const int fr = lane & 15;
    const int fk = (lane >> 4) * 8;
    const int srow = t >> 3;
    const int scol = (t & 7) * 8;

    _Float16 hs[4];
#pragma unroll
    for (int p = 0; p < 4; ++p)
        hs[p] = (_Float16)Wsc[n0 + srow + p * 32];

    f32x4 acc[4][4];
#pragma unroll
    for (int i = 0; i < 4; ++i)
#pragma unroll
        for (int j = 0; j < 4; ++j)
            acc[i][j] = (f32x4){0.f, 0.f, 0.f, 0.f};

    for (int k0 = 0; k0 < K; k0 += 64) {
        __syncthreads();
#pragma unroll
        for (int c = 0; c < 4; ++c) {
            const int rl = c * 32 + srow;
            const float* asrc = A + (size_t)(m0 + rl) * K + (k0 + scol);
            const float4 a0 = ((const float4*)asrc)[0];
            const float4 a1 = ((const float4*)asrc)[1];
            half8 av;
            av[0] = (_Float16)a0.x; av[1] = (_Float16)a0.y;
            av[2] = (_Float16)a0.z; av[3] = (_Float16)a0.w;
            av[4] = (_Float16)a1.x; av[5] = (_Float16)a1.y;
            av[6] = (_Float16)a1.z; av[7] = (_Float16)a1.w;
            *(half8*)&As[rl][scol] = av;
        }
#pragma unroll
        for (int p = 0; p < 4; ++p) {
            const int nl = srow + p * 32;
            const float* wsrc = W + (size_t)(n0 + nl) * K + (k0 + scol);
            const float4 w0 = ((const float4*)wsrc)[0];
            const float4 w1 = ((const float4*)wsrc)[1];
            half8 hv;
            hv[0] = (_Float16)w0.x * hs[p]; hv[1] = (_Float16)w0.y * hs[p];
            hv[2] = (_Float16)w0.z * hs[p]; hv[3] = (_Float16)w0.w * hs[p];
            hv[4] = (_Float16)w1.x * hs[p]; hv[5] = (_Float16)w1.y * hs[p];
            hv[6] = (_Float16)w1.z * hs[p]; hv[7] = (_Float16)w1.w * hs[p];
            *(half8*)&Bs[nl][scol] = hv;
        }
        __syncthreads();
#pragma unroll
        for (int kk = 0; kk < 64; kk += 32) {
            half8 av[4], bv[4];
#pragma unroll
            for (int i = 0; i < 4; ++i)
                av[i] = *(const half8*)&As[wr + i * 16 + fr][kk + fk];
#pragma unroll
            for (int j = 0; j < 4; ++j)
                bv[j] = *(const half8*)&Bs[wc + j * 16 + fr][kk + fk];
#pragma unroll
            for (int i = 0; i < 4; ++i)
#pragma unroll
                for (int j = 0; j < 4; ++j)
                    acc[i][j] = __builtin_amdgcn_mfma_f32_16x16x32_f16(
                        av[i], bv[j], acc[i][j], 0, 0, 0);
        }
    }
#pragma unroll
    for (int i = 0; i < 4; ++i) {
        const int row = m0 + wr + i * 16 + (lane >> 4) * 4;
#pragma unroll
        for (int j = 0; j < 4; ++j) {
            const int col = n0 + wc + j * 16 + fr;
            const float bb = bias[col];
#pragma unroll
            for (int r = 0; r < 4; ++r)
                C[(size_t)(row + r) * N + col] =
                    (float)(_Float16)(acc[i][j][r] + bb);
        }
    }
}

extern "C" void kernel_launch(void* const* d_in, const int* in_sizes, int n_in,
                              void* d_out, int out_size, void* d_ws, size_t ws_size,
                              hipStream_t stream) {
    const float* A    = (const float*)d_in[0];
    const float* W    = (const float*)d_in[1];
    const float* Wsc  = (const float*)d_in[2];
    const float* bias = (const float*)d_in[3];
    float* C = (float*)d_out;

    const size_t a_bytes = (size_t)M * K * sizeof(_Float16);   // 16.78 MB
    const size_t w_bytes = (size_t)N * K * sizeof(_Float16);   // 83.89 MB

    if (ws_size >= a_bytes + w_bytes) {
        _Float16* Ah = (_Float16*)d_ws;
        _Float16* Wh = (_Float16*)((char*)d_ws + a_bytes);
        convert_a_kernel<<<dim3(1024), dim3(256), 0, stream>>>(A, Ah);
        dequant_w_kernel<<<dim3(2048), dim3(256), 0, stream>>>(W, Wsc, Wh);
        const int nwg = (M / BM) * (N / BN);  // 640
        qgemm8p_kernel<<<dim3(nwg), dim3(512), 0, stream>>>(Ah, Wh, bias, C);
    } else {
        const int nwg = (M / 128) * (N / 128);
        qlinear_fused_kernel<<<dim3(nwg), dim3(256), 0, stream>>>(A, W, Wsc, bias, C);
    }
}

// Round 6
// 280.932 us; speedup vs baseline: 1.0620x; 1.0030x over previous
//
#include <hip/hip_runtime.h>
#include <hip/hip_fp16.h>

typedef _Float16 half8 __attribute__((ext_vector_type(8)));
typedef float f32x4 __attribute__((ext_vector_type(4)));

constexpr int M = 2048;    // B*S
constexpr int N = 10240;   // DOUT
constexpr int K = 4096;    // DIN

// ---------------------------------------------------------------------------
// Pre-pass 1: W fp32 -> fp16 * fp16(scale). Bit-identical to reference.
__global__ __launch_bounds__(256)
void dequant_w_kernel(const float* __restrict__ W, const float* __restrict__ Wsc,
                      _Float16* __restrict__ Wh) {
    const long total = (long)N * K / 8;
    for (long i = (long)blockIdx.x * blockDim.x + threadIdx.x; i < total;
         i += (long)gridDim.x * blockDim.x) {
        const long base = i * 8;
        const int row = (int)(base >> 12);           // / K
        const _Float16 s = (_Float16)Wsc[row];
        const float4 w0 = ((const float4*)(W + base))[0];
        const float4 w1 = ((const float4*)(W + base))[1];
        half8 h;
        h[0] = (_Float16)w0.x * s; h[1] = (_Float16)w0.y * s;
        h[2] = (_Float16)w0.z * s; h[3] = (_Float16)w0.w * s;
        h[4] = (_Float16)w1.x * s; h[5] = (_Float16)w1.y * s;
        h[6] = (_Float16)w1.z * s; h[7] = (_Float16)w1.w * s;
        *(half8*)(Wh + base) = h;
    }
}

// Pre-pass 2: A fp32 (fp16-valued) -> fp16 (exact).
__global__ __launch_bounds__(256)
void convert_a_kernel(const float* __restrict__ A, _Float16* __restrict__ Ah) {
    const long total = (long)M * K / 8;
    for (long i = (long)blockIdx.x * blockDim.x + threadIdx.x; i < total;
         i += (long)gridDim.x * blockDim.x) {
        const long base = i * 8;
        const float4 a0 = ((const float4*)(A + base))[0];
        const float4 a1 = ((const float4*)(A + base))[1];
        half8 h;
        h[0] = (_Float16)a0.x; h[1] = (_Float16)a0.y;
        h[2] = (_Float16)a0.z; h[3] = (_Float16)a0.w;
        h[4] = (_Float16)a1.x; h[5] = (_Float16)a1.y;
        h[6] = (_Float16)a1.z; h[7] = (_Float16)a1.w;
        *(half8*)(Ah + base) = h;
    }
}

// ---------------------------------------------------------------------------
// 256x256 GEMM, m201 wave geometry: 8 waves (2M x 4N) of 128x64 each.
// T2 swizzle (linear gload_lds dest + pre-swizzled src + swizzled ds_read),
// T3+T4 counted vmcnt(8) distance-2 prefetch, T5 setprio around MFMA.
//
// Per-phase balance per SIMD (2 waves): MFMA 16x2x19.4 = 620 cy vs
// LDS reads <= 48 KB/CU-phase = 565 cy -> MFMA-dominant (m201 regime).
//
// Buffer lifetime ledger:
//   reads: aT,b0 @P0; b1 @P1; aB @P2. Wave's ds_reads complete before its
//   MFMA (data dep), MFMA precedes phase-end barrier. Hence after P1-end
//   barrier ALL waves consumed B(cur); after P2-end barrier A(cur).
//   Stage B(t+2)->cur at P2, A(t+2)->cur at P3. vmcnt(8) at P3 = t+1's 8
//   loads landed, t+2's 8 in flight. Never drain to 0 mid-loop.
constexpr int BM = 256, BN = 256, BK = 64;
constexpr int AELE = BM * BK;   // 16384 fp16 = 32 KB
constexpr int BELE = BN * BK;   // 16384 fp16 = 32 KB
constexpr int NT = K / BK;      // 64 K-tiles

#define BAR()   asm volatile("s_barrier" ::: "memory")
#define LGKM0() asm volatile("s_waitcnt lgkmcnt(0)" ::: "memory")

__device__ __forceinline__ half8 lds_rd(const _Float16* base, int row, int eo) {
    // T2: physical 16B slot = slot ^ (row&7)
    const int ps = (eo >> 3) ^ (row & 7);
    return *(const half8*)(base + row * BK + ps * 8);
}

__global__ __launch_bounds__(512, 1)
void qgemm256_kernel(const _Float16* __restrict__ Ag,  // [M,K] fp16 (ws)
                     const _Float16* __restrict__ Wg,  // [N,K] fp16 dequant (ws)
                     const float*    __restrict__ bias,
                     float*          __restrict__ C)
{
    __shared__ _Float16 AsF[2 * AELE];   // 64 KB
    __shared__ _Float16 BsF[2 * BELE];   // 64 KB

    // XCD-bijective swizzle: nwg=320, chunks of 40, brow-fast (8 consecutive
    // blocks share one 2MB B panel -> L2-resident per XCD).
    const int orig = blockIdx.x;
    const int wgid = (orig & 7) * 40 + (orig >> 3);
    const int m0 = (wgid & 7) * BM;
    const int n0 = (wgid >> 3) * BN;

    const int tid  = threadIdx.x;
    const int lane = tid & 63;
    const int w    = tid >> 6;
    const int wm   = w >> 2;            // 0..1 -> rows wm*128
    const int wn   = w & 3;             // 0..3 -> cols wn*64
    const int fr   = lane & 15;
    const int fkE  = (lane >> 4) * 8;

    const int trow  = tid >> 3;                        // staging row 0..63
    const int swcol = (((tid & 7) ^ (trow & 7))) * 8;  // pre-swizzled src col

    // stage unit = 64 rows x 64 cols fp16 = 8 KB = 512 thr x 16 B
    auto stage_a = [&](int b, int u, int kcol) {
        const _Float16* src = Ag + (size_t)(m0 + u * 64 + trow) * K + (kcol + swcol);
        __builtin_amdgcn_global_load_lds(
            (const __attribute__((address_space(1))) void*)src,
            (__attribute__((address_space(3))) void*)(AsF + b * AELE + u * 4096 + tid * 8),
            16, 0, 0);
    };
    auto stage_b = [&](int b, int u, int kcol) {
        const _Float16* src = Wg + (size_t)(n0 + u * 64 + trow) * K + (kcol + swcol);
        __builtin_amdgcn_global_load_lds(
            (const __attribute__((address_space(1))) void*)src,
            (__attribute__((address_space(3))) void*)(BsF + b * BELE + u * 4096 + tid * 8),
            16, 0, 0);
    };

    f32x4 acc[8][4];
#pragma unroll
    for (int i = 0; i < 8; ++i)
#pragma unroll
        for (int j = 0; j < 4; ++j)
            acc[i][j] = (f32x4){0.f, 0.f, 0.f, 0.f};

    // prologue: tile0 -> buf0 (8 loads), tile1 -> buf1 (8 loads)
#pragma unroll
    for (int u = 0; u < 4; ++u) { stage_a(0, u, 0); stage_b(0, u, 0); }
    if (NT > 1) {
#pragma unroll
        for (int u = 0; u < 4; ++u) { stage_a(1, u, BK); stage_b(1, u, BK); }
        asm volatile("s_waitcnt vmcnt(8)" ::: "memory");   // tile0 landed
    } else {
        asm volatile("s_waitcnt vmcnt(0)" ::: "memory");
    }
    BAR();

#pragma unroll 1
    for (int t = 0; t < NT; ++t) {
        const int cur = t & 1;
        const _Float16* Ab = AsF + cur * AELE;
        const _Float16* Bb = BsF + cur * BELE;
        const bool pf2 = (t + 2 < NT);
        const int k2 = (t + 2) * BK;

        half8 aT[4][2], aB[4][2], b0[2][2], b1[2][2];

        // ---- P0: read aT (8) + b0 (4); MFMA quadrant (top, j0)
#pragma unroll
        for (int ii = 0; ii < 4; ++ii)
#pragma unroll
            for (int kh = 0; kh < 2; ++kh)
                aT[ii][kh] = lds_rd(Ab, wm * 128 + ii * 16 + fr, kh * 32 + fkE);
#pragma unroll
        for (int jj = 0; jj < 2; ++jj)
#pragma unroll
            for (int kh = 0; kh < 2; ++kh)
                b0[jj][kh] = lds_rd(Bb, wn * 64 + jj * 16 + fr, kh * 32 + fkE);
        BAR(); LGKM0();
        __builtin_amdgcn_s_setprio(1);
#pragma unroll
        for (int ii = 0; ii < 4; ++ii)
#pragma unroll
            for (int jj = 0; jj < 2; ++jj)
#pragma unroll
                for (int kh = 0; kh < 2; ++kh)
                    acc[ii][jj] = __builtin_amdgcn_mfma_f32_16x16x32_f16(
                        aT[ii][kh], b0[jj][kh], acc[ii][jj], 0, 0, 0);
        __builtin_amdgcn_s_setprio(0);
        BAR();

        // ---- P1: read b1 (4); MFMA quadrant (top, j1)
#pragma unroll
        for (int jj = 0; jj < 2; ++jj)
#pragma unroll
            for (int kh = 0; kh < 2; ++kh)
                b1[jj][kh] = lds_rd(Bb, wn * 64 + 32 + jj * 16 + fr, kh * 32 + fkE);
        BAR(); LGKM0();
        __builtin_amdgcn_s_setprio(1);
#pragma unroll
        for (int ii = 0; ii < 4; ++ii)
#pragma unroll
            for (int jj = 0; jj < 2; ++jj)
#pragma unroll
                for (int kh = 0; kh < 2; ++kh)
                    acc[ii][2 + jj] = __builtin_amdgcn_mfma_f32_16x16x32_f16(
                        aT[ii][kh], b1[jj][kh], acc[ii][2 + jj], 0, 0, 0);
        __builtin_amdgcn_s_setprio(0);
        BAR();   // <- B(cur) fully consumed

        // ---- P2: read aB (8); stage B(t+2) -> cur; MFMA quadrant (bot, j0)
#pragma unroll
        for (int ii = 0; ii < 4; ++ii)
#pragma unroll
            for (int kh = 0; kh < 2; ++kh)
                aB[ii][kh] = lds_rd(Ab, wm * 128 + 64 + ii * 16 + fr, kh * 32 + fkE);
        if (pf2) {
#pragma unroll
            for (int u = 0; u < 4; ++u) stage_b(cur, u, k2);
        }
        BAR(); LGKM0();
        __builtin_amdgcn_s_setprio(1);
#pragma unroll
        for (int ii = 0; ii < 4; ++ii)
#pragma unroll
            for (int jj = 0; jj < 2; ++jj)
#pragma unroll
                for (int kh = 0; kh < 2; ++kh)
                    acc[4 + ii][jj] = __builtin_amdgcn_mfma_f32_16x16x32_f16(
                        aB[ii][kh], b0[jj][kh], acc[4 + ii][jj], 0, 0, 0);
        __builtin_amdgcn_s_setprio(0);
        BAR();   // <- A(cur) fully consumed

        // ---- P3: stage A(t+2) -> cur; MFMA quadrant (bot, j1); counted vmcnt
        if (pf2) {
#pragma unroll
            for (int u = 0; u < 4; ++u) stage_a(cur, u, k2);
        }
        __builtin_amdgcn_s_setprio(1);
#pragma unroll
        for (int ii = 0; ii < 4; ++ii)
#pragma unroll
            for (int jj = 0; jj < 2; ++jj)
#pragma unroll
                for (int kh = 0; kh < 2; ++kh)
                    acc[4 + ii][2 + jj] = __builtin_amdgcn_mfma_f32_16x16x32_f16(
                        aB[ii][kh], b1[jj][kh], acc[4 + ii][2 + jj], 0, 0, 0);
        __builtin_amdgcn_s_setprio(0);
        if (pf2) asm volatile("s_waitcnt vmcnt(8)" ::: "memory");  // t+1 landed
        else     asm volatile("s_waitcnt vmcnt(0)" ::: "memory");  // tail drain
        BAR();
    }

    // epilogue: C/D layout col = lane&15, row = (lane>>4)*4 + reg
    float bb[4];
#pragma unroll
    for (int j = 0; j < 4; ++j)
        bb[j] = bias[n0 + wn * 64 + j * 16 + fr];
#pragma unroll
    for (int i = 0; i < 8; ++i) {
        const int row = m0 + wm * 128 + i * 16 + (lane >> 4) * 4;
#pragma unroll
        for (int j = 0; j < 4; ++j) {
            const int col = n0 + wn * 64 + j * 16 + fr;
#pragma unroll
            for (int r = 0; r < 4; ++r)
                C[(size_t)(row + r) * N + col] =
                    (float)(_Float16)(acc[i][j][r] + bb[j]);
        }
    }
}

// ---------------------------------------------------------------------------
// Fallback (round-2 fused kernel, passing @434us) if ws too small.
__global__ __launch_bounds__(256, 2)
void qlinear_fused_kernel(const float* __restrict__ A, const float* __restrict__ W,
                          const float* __restrict__ Wsc, const float* __restrict__ bias,
                          float* __restrict__ C)
{
    __shared__ _Float16 As[128][64];
    __shared__ _Float16 Bs[128][64];

    const int nwg  = (M / 128) * (N / 128);
    const int orig = blockIdx.x;
    const int wgid = (orig & 7) * (nwg >> 3) + (orig >> 3);
    const int brow = wgid & (M / 128 - 1);
    const int bcol = wgid / (M / 128);
    const int m0 = brow * 128;
    const int n0 = bcol * 128;

    const int t    = threadIdx.x;
    const int lane = t & 63;
    const int wave = t >> 6;
    const int wr = (wave >> 1) * 64;
    const int wc = (wave & 1) * 64;
    const int fr = lane & 15;
    const int fk = (lane >> 4) * 8;
    const int srow = t >> 3;
    const int scol = (t & 7) * 8;

    _Float16 hs[4];
#pragma unroll
    for (int p = 0; p < 4; ++p)
        hs[p] = (_Float16)Wsc[n0 + srow + p * 32];

    f32x4 acc[4][4];
#pragma unroll
    for (int i = 0; i < 4; ++i)
#pragma unroll
        for (int j = 0; j < 4; ++j)
            acc[i][j] = (f32x4){0.f, 0.f, 0.f, 0.f};

    for (int k0 = 0; k0 < K; k0 += 64) {
        __syncthreads();
#pragma unroll
        for (int c = 0; c < 4; ++c) {
            const int rl = c * 32 + srow;
            const float* asrc = A + (size_t)(m0 + rl) * K + (k0 + scol);
            const float4 a0 = ((const float4*)asrc)[0];
            const float4 a1 = ((const float4*)asrc)[1];
            half8 av;
            av[0] = (_Float16)a0.x; av[1] = (_Float16)a0.y;
            av[2] = (_Float16)a0.z; av[3] = (_Float16)a0.w;
            av[4] = (_Float16)a1.x; av[5] = (_Float16)a1.y;
            av[6] = (_Float16)a1.z; av[7] = (_Float16)a1.w;
            *(half8*)&As[rl][scol] = av;
        }
#pragma unroll
        for (int p = 0; p < 4; ++p) {
            const int nl = srow + p * 32;
            const float* wsrc = W + (size_t)(n0 + nl) * K + (k0 + scol);
            const float4 w0 = ((const float4*)wsrc)[0];
            const float4 w1 = ((const float4*)wsrc)[1];
            half8 hv;
            hv[0] = (_Float16)w0.x * hs[p]; hv[1] = (_Float16)w0.y * hs[p];
            hv[2] = (_Float16)w0.z * hs[p]; hv[3] = (_Float16)w0.w * hs[p];
            hv[4] = (_Float16)w1.x * hs[p]; hv[5] = (_Float16)w1.y * hs[p];
            hv[6] = (_Float16)w1.z * hs[p]; hv[7] = (_Float16)w1.w * hs[p];
            *(half8*)&Bs[nl][scol] = hv;
        }
        __syncthreads();
#pragma unroll
        for (int kk = 0; kk < 64; kk += 32) {
            half8 av[4], bv[4];
#pragma unroll
            for (int i = 0; i < 4; ++i)
                av[i] = *(const half8*)&As[wr + i * 16 + fr][kk + fk];
#pragma unroll
            for (int j = 0; j < 4; ++j)
                bv[j] = *(const half8*)&Bs[wc + j * 16 + fr][kk + fk];
#pragma unroll
            for (int i = 0; i < 4; ++i)
#pragma unroll
                for (int j = 0; j < 4; ++j)
                    acc[i][j] = __builtin_amdgcn_mfma_f32_16x16x32_f16(
                        av[i], bv[j], acc[i][j], 0, 0, 0);
        }
    }
#pragma unroll
    for (int i = 0; i < 4; ++i) {
        const int row = m0 + wr + i * 16 + (lane >> 4) * 4;
#pragma unroll
        for (int j = 0; j < 4; ++j) {
            const int col = n0 + wc + j * 16 + fr;
            const float bbf = bias[col];
#pragma unroll
            for (int r = 0; r < 4; ++r)
                C[(size_t)(row + r) * N + col] =
                    (float)(_Float16)(acc[i][j][r] + bbf);
        }
    }
}

extern "C" void kernel_launch(void* const* d_in, const int* in_sizes, int n_in,
                              void* d_out, int out_size, void* d_ws, size_t ws_size,
                              hipStream_t stream) {
    const float* A    = (const float*)d_in[0];
    const float* W    = (const float*)d_in[1];
    const float* Wsc  = (const float*)d_in[2];
    const float* bias = (const float*)d_in[3];
    float* C = (float*)d_out;

    const size_t a_bytes = (size_t)M * K * sizeof(_Float16);   // 16.78 MB
    const size_t w_bytes = (size_t)N * K * sizeof(_Float16);   // 83.89 MB

    if (ws_size >= a_bytes + w_bytes) {
        _Float16* Ah = (_Float16*)d_ws;
        _Float16* Wh = (_Float16*)((char*)d_ws + a_bytes);
        convert_a_kernel<<<dim3(1024), dim3(256), 0, stream>>>(A, Ah);
        dequant_w_kernel<<<dim3(2048), dim3(256), 0, stream>>>(W, Wsc, Wh);
        const int nwg = (M / BM) * (N / BN);  // 320
        qgemm256_kernel<<<dim3(nwg), dim3(512), 0, stream>>>(Ah, Wh, bias, C);
    } else {
        const int nwg = (M / 128) * (N / 128);
        qlinear_fused_kernel<<<dim3(nwg), dim3(256), 0, stream>>>(A, W, Wsc, bias, C);
    }
}

// Round 7
// 231.471 us; speedup vs baseline: 1.2889x; 1.2137x over previous
//
#include <hip/hip_runtime.h>
#include <hip/hip_fp16.h>

typedef _Float16 half8 __attribute__((ext_vector_type(8)));
typedef float f32x4 __attribute__((ext_vector_type(4)));

constexpr int M = 2048;    // B*S
constexpr int N = 10240;   // DOUT
constexpr int K = 4096;    // DIN

// ---------------------------------------------------------------------------
// Pre-pass 1: W fp32 -> fp16 * fp16(scale). Bit-identical to reference.
__global__ __launch_bounds__(256)
void dequant_w_kernel(const float* __restrict__ W, const float* __restrict__ Wsc,
                      _Float16* __restrict__ Wh) {
    const long total = (long)N * K / 8;
    for (long i = (long)blockIdx.x * blockDim.x + threadIdx.x; i < total;
         i += (long)gridDim.x * blockDim.x) {
        const long base = i * 8;
        const int row = (int)(base >> 12);           // / K
        const _Float16 s = (_Float16)Wsc[row];
        const float4 w0 = ((const float4*)(W + base))[0];
        const float4 w1 = ((const float4*)(W + base))[1];
        half8 h;
        h[0] = (_Float16)w0.x * s; h[1] = (_Float16)w0.y * s;
        h[2] = (_Float16)w0.z * s; h[3] = (_Float16)w0.w * s;
        h[4] = (_Float16)w1.x * s; h[5] = (_Float16)w1.y * s;
        h[6] = (_Float16)w1.z * s; h[7] = (_Float16)w1.w * s;
        *(half8*)(Wh + base) = h;
    }
}

// Pre-pass 2: A fp32 (fp16-valued) -> fp16 (exact).
__global__ __launch_bounds__(256)
void convert_a_kernel(const float* __restrict__ A, _Float16* __restrict__ Ah) {
    const long total = (long)M * K / 8;
    for (long i = (long)blockIdx.x * blockDim.x + threadIdx.x; i < total;
         i += (long)gridDim.x * blockDim.x) {
        const long base = i * 8;
        const float4 a0 = ((const float4*)(A + base))[0];
        const float4 a1 = ((const float4*)(A + base))[1];
        half8 h;
        h[0] = (_Float16)a0.x; h[1] = (_Float16)a0.y;
        h[2] = (_Float16)a0.z; h[3] = (_Float16)a0.w;
        h[4] = (_Float16)a1.x; h[5] = (_Float16)a1.y;
        h[6] = (_Float16)a1.z; h[7] = (_Float16)a1.w;
        *(half8*)(Ah + base) = h;
    }
}

// ---------------------------------------------------------------------------
// 128x320 GEMM: 16x32 = 512 blocks = EXACTLY 2 scheduling rounds (no tail).
// 8 waves (2M x 4N) of 64x80; acc[4][5]. 2 barriers/tile, front-loaded
// ds_reads overlapping MFMA-g1 via compiler counted lgkm waits; stage for
// t+2 overlaps register-only MFMA-g2; counted vmcnt(7) (T4, never 0).
// T2 swizzle: linear gload_lds dest + pre-swizzled src col + swizzled read.
//
// Lifetime ledger: all 18 ds_reads of tile t issued in P0; each wave does
// lgkmcnt(0) before BAR1 -> after BAR1 every wave's reads of BOTH regions
// are complete -> stage t+2 into cur is safe. MFMA-g2 uses registers only.
// vmcnt(7) at tile end: outstanding = t+2's 7 + t+1's 7 -> waits t+1's,
// leaves t+2's in flight. BAR2 publishes t+1.
constexpr int BM = 128, BN = 320, BK = 64;
constexpr int AELE = BM * BK;   // 8192  fp16 = 16 KB
constexpr int BELE = BN * BK;   // 20480 fp16 = 40 KB
constexpr int NT = K / BK;      // 64 K-tiles

#define BAR()   asm volatile("s_barrier" ::: "memory")
#define LGKM0() asm volatile("s_waitcnt lgkmcnt(0)" ::: "memory")

__device__ __forceinline__ half8 lds_rd(const _Float16* base, int row, int eo) {
    // T2: physical 16B slot = slot ^ (row&7)
    const int ps = (eo >> 3) ^ (row & 7);
    return *(const half8*)(base + row * BK + ps * 8);
}

__global__ __launch_bounds__(512, 1)
void qgemm320_kernel(const _Float16* __restrict__ Ag,  // [M,K] fp16 (ws)
                     const _Float16* __restrict__ Wg,  // [N,K] fp16 dequant (ws)
                     const float*    __restrict__ bias,
                     float*          __restrict__ C)
{
    __shared__ _Float16 AsF[2 * AELE];   // 32 KB
    __shared__ _Float16 BsF[2 * BELE];   // 80 KB

    // XCD-bijective swizzle: 512 = 8 XCD x 64; within a chunk brow-fast ->
    // 16-block runs share one 2.6MB B panel (L2-resident per XCD).
    const int orig = blockIdx.x;
    const int wgid = (orig & 7) * 64 + (orig >> 3);
    const int m0 = (wgid & 15) * BM;
    const int n0 = (wgid >> 4) * BN;

    const int tid  = threadIdx.x;
    const int lane = tid & 63;
    const int w    = tid >> 6;
    const int wm   = w >> 2;            // 0..1 -> rows wm*64
    const int wn   = w & 3;             // 0..3 -> cols wn*80
    const int fr   = lane & 15;
    const int fkE  = (lane >> 4) * 8;

    const int trow  = tid >> 3;                        // staging row 0..63
    const int swcol = (((tid & 7) ^ (trow & 7))) * 8;  // pre-swizzled src col

    // stage unit = 64 rows x 64 cols fp16 = 8 KB = 512 thr x 16 B
    auto stage_a = [&](int b, int u, int kcol) {
        const _Float16* src = Ag + (size_t)(m0 + u * 64 + trow) * K + (kcol + swcol);
        __builtin_amdgcn_global_load_lds(
            (const __attribute__((address_space(1))) void*)src,
            (__attribute__((address_space(3))) void*)(AsF + b * AELE + u * 4096 + tid * 8),
            16, 0, 0);
    };
    auto stage_b = [&](int b, int u, int kcol) {
        const _Float16* src = Wg + (size_t)(n0 + u * 64 + trow) * K + (kcol + swcol);
        __builtin_amdgcn_global_load_lds(
            (const __attribute__((address_space(1))) void*)src,
            (__attribute__((address_space(3))) void*)(BsF + b * BELE + u * 4096 + tid * 8),
            16, 0, 0);
    };

    f32x4 acc[4][5];
#pragma unroll
    for (int i = 0; i < 4; ++i)
#pragma unroll
        for (int j = 0; j < 5; ++j)
            acc[i][j] = (f32x4){0.f, 0.f, 0.f, 0.f};

    // prologue: tile0 -> buf0 (7 loads), tile1 -> buf1 (7 loads)
    stage_a(0, 0, 0); stage_a(0, 1, 0);
#pragma unroll
    for (int u = 0; u < 5; ++u) stage_b(0, u, 0);
    stage_a(1, 0, BK); stage_a(1, 1, BK);
#pragma unroll
    for (int u = 0; u < 5; ++u) stage_b(1, u, BK);
    asm volatile("s_waitcnt vmcnt(7)" ::: "memory");   // tile0 landed
    BAR();

#pragma unroll 1
    for (int t = 0; t < NT; ++t) {
        const int cur = t & 1;
        const _Float16* Ab = AsF + cur * AELE;
        const _Float16* Bb = BsF + cur * BELE;
        const bool pf2 = (t + 2 < NT);
        const int k2 = (t + 2) * BK;

        half8 af[4][2], bf[5][2];

        // ---- P0: issue ALL 18 ds_reads (A first, then B)
#pragma unroll
        for (int rb = 0; rb < 4; ++rb)
#pragma unroll
            for (int kh = 0; kh < 2; ++kh)
                af[rb][kh] = lds_rd(Ab, wm * 64 + rb * 16 + fr, kh * 32 + fkE);
#pragma unroll
        for (int cb = 0; cb < 5; ++cb)
#pragma unroll
            for (int kh = 0; kh < 2; ++kh)
                bf[cb][kh] = lds_rd(Bb, wn * 80 + cb * 16 + fr, kh * 32 + fkE);

        // MFMA g1: A x Bcols{0,1,2} (24 MFMA) — compiler emits counted lgkm
        // waits, so late B reads drain UNDER these MFMAs.
        __builtin_amdgcn_s_setprio(1);
#pragma unroll
        for (int rb = 0; rb < 4; ++rb)
#pragma unroll
            for (int cb = 0; cb < 3; ++cb)
#pragma unroll
                for (int kh = 0; kh < 2; ++kh)
                    acc[rb][cb] = __builtin_amdgcn_mfma_f32_16x16x32_f16(
                        af[rb][kh], bf[cb][kh], acc[rb][cb], 0, 0, 0);
        __builtin_amdgcn_s_setprio(0);

        LGKM0();   // all own reads complete (cross-wave safety for staging)
        BAR();     // -> every wave's reads of A(cur)+B(cur) are done

        // ---- P1: stage tile t+2 into cur (regions free); MFMA g2 (reg-only)
        if (pf2) {
            stage_a(cur, 0, k2); stage_a(cur, 1, k2);
#pragma unroll
            for (int u = 0; u < 5; ++u) stage_b(cur, u, k2);
        }
        __builtin_amdgcn_s_setprio(1);
#pragma unroll
        for (int rb = 0; rb < 4; ++rb)
#pragma unroll
            for (int cb = 3; cb < 5; ++cb)
#pragma unroll
                for (int kh = 0; kh < 2; ++kh)
                    acc[rb][cb] = __builtin_amdgcn_mfma_f32_16x16x32_f16(
                        af[rb][kh], bf[cb][kh], acc[rb][cb], 0, 0, 0);
        __builtin_amdgcn_s_setprio(0);

        if (pf2) asm volatile("s_waitcnt vmcnt(7)" ::: "memory");  // t+1 landed
        else     asm volatile("s_waitcnt vmcnt(0)" ::: "memory");  // tail drain
        BAR();   // publish t+1
    }

    // epilogue: C/D layout col = lane&15, row = (lane>>4)*4 + reg
    float bb[5];
#pragma unroll
    for (int j = 0; j < 5; ++j)
        bb[j] = bias[n0 + wn * 80 + j * 16 + fr];
#pragma unroll
    for (int i = 0; i < 4; ++i) {
        const int row = m0 + wm * 64 + i * 16 + (lane >> 4) * 4;
#pragma unroll
        for (int j = 0; j < 5; ++j) {
            const int col = n0 + wn * 80 + j * 16 + fr;
#pragma unroll
            for (int r = 0; r < 4; ++r)
                C[(size_t)(row + r) * N + col] =
                    (float)(_Float16)(acc[i][j][r] + bb[j]);
        }
    }
}

// ---------------------------------------------------------------------------
// Fallback (round-2 fused kernel, passing @434us) if ws too small.
__global__ __launch_bounds__(256, 2)
void qlinear_fused_kernel(const float* __restrict__ A, const float* __restrict__ W,
                          const float* __restrict__ Wsc, const float* __restrict__ bias,
                          float* __restrict__ C)
{
    __shared__ _Float16 As[128][64];
    __shared__ _Float16 Bs[128][64];

    const int nwg  = (M / 128) * (N / 128);
    const int orig = blockIdx.x;
    const int wgid = (orig & 7) * (nwg >> 3) + (orig >> 3);
    const int brow = wgid & (M / 128 - 1);
    const int bcol = wgid / (M / 128);
    const int m0 = brow * 128;
    const int n0 = bcol * 128;

    const int t    = threadIdx.x;
    const int lane = t & 63;
    const int wave = t >> 6;
    const int wr = (wave >> 1) * 64;
    const int wc = (wave & 1) * 64;
    const int fr = lane & 15;
    const int fk = (lane >> 4) * 8;
    const int srow = t >> 3;
    const int scol = (t & 7) * 8;

    _Float16 hs[4];
#pragma unroll
    for (int p = 0; p < 4; ++p)
        hs[p] = (_Float16)Wsc[n0 + srow + p * 32];

    f32x4 acc[4][4];
#pragma unroll
    for (int i = 0; i < 4; ++i)
#pragma unroll
        for (int j = 0; j < 4; ++j)
            acc[i][j] = (f32x4){0.f, 0.f, 0.f, 0.f};

    for (int k0 = 0; k0 < K; k0 += 64) {
        __syncthreads();
#pragma unroll
        for (int c = 0; c < 4; ++c) {
            const int rl = c * 32 + srow;
            const float* asrc = A + (size_t)(m0 + rl) * K + (k0 + scol);
            const float4 a0 = ((const float4*)asrc)[0];
            const float4 a1 = ((const float4*)asrc)[1];
            half8 av;
            av[0] = (_Float16)a0.x; av[1] = (_Float16)a0.y;
            av[2] = (_Float16)a0.z; av[3] = (_Float16)a0.w;
            av[4] = (_Float16)a1.x; av[5] = (_Float16)a1.y;
            av[6] = (_Float16)a1.z; av[7] = (_Float16)a1.w;
            *(half8*)&As[rl][scol] = av;
        }
#pragma unroll
        for (int p = 0; p < 4; ++p) {
            const int nl = srow + p * 32;
            const float* wsrc = W + (size_t)(n0 + nl) * K + (k0 + scol);
            const float4 w0 = ((const float4*)wsrc)[0];
            const float4 w1 = ((const float4*)wsrc)[1];
            half8 hv;
            hv[0] = (_Float16)w0.x * hs[p]; hv[1] = (_Float16)w0.y * hs[p];
            hv[2] = (_Float16)w0.z * hs[p]; hv[3] = (_Float16)w0.w * hs[p];
            hv[4] = (_Float16)w1.x * hs[p]; hv[5] = (_Float16)w1.y * hs[p];
            hv[6] = (_Float16)w1.z * hs[p]; hv[7] = (_Float16)w1.w * hs[p];
            *(half8*)&Bs[nl][scol] = hv;
        }
        __syncthreads();
#pragma unroll
        for (int kk = 0; kk < 64; kk += 32) {
            half8 av[4], bv[4];
#pragma unroll
            for (int i = 0; i < 4; ++i)
                av[i] = *(const half8*)&As[wr + i * 16 + fr][kk + fk];
#pragma unroll
            for (int j = 0; j < 4; ++j)
                bv[j] = *(const half8*)&Bs[wc + j * 16 + fr][kk + fk];
#pragma unroll
            for (int i = 0; i < 4; ++i)
#pragma unroll
                for (int j = 0; j < 4; ++j)
                    acc[i][j] = __builtin_amdgcn_mfma_f32_16x16x32_f16(
                        av[i], bv[j], acc[i][j], 0, 0, 0);
        }
    }
#pragma unroll
    for (int i = 0; i < 4; ++i) {
        const int row = m0 + wr + i * 16 + (lane >> 4) * 4;
#pragma unroll
        for (int j = 0; j < 4; ++j) {
            const int col = n0 + wc + j * 16 + fr;
            const float bbf = bias[col];
#pragma unroll
            for (int r = 0; r < 4; ++r)
                C[(size_t)(row + r) * N + col] =
                    (float)(_Float16)(acc[i][j][r] + bbf);
        }
    }
}

extern "C" void kernel_launch(void* const* d_in, const int* in_sizes, int n_in,
                              void* d_out, int out_size, void* d_ws, size_t ws_size,
                              hipStream_t stream) {
    const float* A    = (const float*)d_in[0];
    const float* W    = (const float*)d_in[1];
    const float* Wsc  = (const float*)d_in[2];
    const float* bias = (const float*)d_in[3];
    float* C = (float*)d_out;

    const size_t a_bytes = (size_t)M * K * sizeof(_Float16);   // 16.78 MB
    const size_t w_bytes = (size_t)N * K * sizeof(_Float16);   // 83.89 MB

    if (ws_size >= a_bytes + w_bytes) {
        _Float16* Ah = (_Float16*)d_ws;
        _Float16* Wh = (_Float16*)((char*)d_ws + a_bytes);
        convert_a_kernel<<<dim3(1024), dim3(256), 0, stream>>>(A, Ah);
        dequant_w_kernel<<<dim3(2048), dim3(256), 0, stream>>>(W, Wsc, Wh);
        const int nwg = (M / BM) * (N / BN);  // 512
        qgemm320_kernel<<<dim3(nwg), dim3(512), 0, stream>>>(Ah, Wh, bias, C);
    } else {
        const int nwg = (M / 128) * (N / 128);
        qlinear_fused_kernel<<<dim3(nwg), dim3(256), 0, stream>>>(A, W, Wsc, bias, C);
    }
}